// Round 10
// baseline (387.307 us; speedup 1.0000x reference)
//
#include <hip/hip_runtime.h>

#define NFEAT 128
#define NCLS  10
#define NCP   16    // padded class count
#define BROW  512   // rows per bucket
#define BINC  4096  // items per binning chunk

static inline size_t alignup(size_t x) { return (x + 255) & ~size_t(255); }

// bf16 helpers (bit-level, RNE)
__device__ __forceinline__ ushort f2bf(float f) {
  uint x = __float_as_uint(f);
  return (ushort)((x + 0x7fffu + ((x >> 16) & 1u)) >> 16);
}
__device__ __forceinline__ float bf2f(ushort u) {
  return __uint_as_float(((uint)u) << 16);
}

typedef short bf16x8 __attribute__((ext_vector_type(8)));
typedef float f32x4 __attribute__((ext_vector_type(4)));

// ---------------- CSR build (bucketed, write-amplification-free) ----------------

__global__ __launch_bounds__(256) void bucket_hist(const int* __restrict__ dst,
                                                   int* __restrict__ bkt_cnt,
                                                   int e, int nbkt) {
  __shared__ int hist[256];
  for (int t = threadIdx.x; t < nbkt; t += 256) hist[t] = 0;
  __syncthreads();
  int i = blockIdx.x * 256 + threadIdx.x;
  int stride = gridDim.x * 256;
  for (; i < e; i += stride) atomicAdd(&hist[dst[i] >> 9], 1);
  __syncthreads();
  for (int t = threadIdx.x; t < nbkt; t += 256)
    if (hist[t]) atomicAdd(&bkt_cnt[t], hist[t]);
}

__global__ __launch_bounds__(256) void bkt_scan(const int* __restrict__ bkt_cnt,
                                                int* __restrict__ bkt_off,
                                                int* __restrict__ gfrontier,
                                                int n, int nbkt) {
  __shared__ int sbuf[256];
  const int t = threadIdx.x;
  int x = 0;
  if (t < nbkt) {
    int lo = t << 9;
    int nodes = n - lo; if (nodes > BROW) nodes = BROW;
    x = bkt_cnt[t] + nodes;
  }
  sbuf[t] = x;
  __syncthreads();
  for (int off = 1; off < 256; off <<= 1) {
    int v = (t >= off) ? sbuf[t - off] : 0;
    __syncthreads();
    sbuf[t] += v;
    __syncthreads();
  }
  if (t < nbkt) { bkt_off[t] = sbuf[t] - x; gfrontier[t] = sbuf[t] - x; }
  if (t == nbkt - 1) bkt_off[nbkt] = sbuf[t];
}

__global__ __launch_bounds__(256) void bin_items(const int* __restrict__ ei,
                                                 int nE, int total, int nbkt,
                                                 int* __restrict__ gfrontier,
                                                 int2* __restrict__ binned) {
  __shared__ int hist[256];
  __shared__ int loff[256];
  __shared__ int gbase[256];
  __shared__ int sbuf[256];
  __shared__ int2 st[BINC];
  const int t = threadIdx.x;
  const int chunk0 = blockIdx.x * BINC;
  for (int q = t; q < nbkt; q += 256) hist[q] = 0;
  __syncthreads();
  for (int j = t; j < BINC; j += 256) {
    int i = chunk0 + j;
    if (i < total) {
      int d = (i < nE) ? ei[nE + i] : (i - nE);
      atomicAdd(&hist[d >> 9], 1);
    }
  }
  __syncthreads();
  int x = (t < nbkt) ? hist[t] : 0;
  sbuf[t] = x;
  __syncthreads();
  for (int off = 1; off < 256; off <<= 1) {
    int v = (t >= off) ? sbuf[t - off] : 0;
    __syncthreads();
    sbuf[t] += v;
    __syncthreads();
  }
  loff[t] = sbuf[t] - x;
  gbase[t] = (t < nbkt && x > 0) ? atomicAdd(&gfrontier[t], x) : 0;
  __syncthreads();
  hist[t] = loff[t];
  __syncthreads();
  for (int j = t; j < BINC; j += 256) {
    int i = chunk0 + j;
    if (i < total) {
      int s, d;
      if (i < nE) { s = ei[i]; d = ei[nE + i]; }
      else        { s = i - nE; d = s; }
      int p = atomicAdd(&hist[d >> 9], 1);
      st[p] = make_int2(s, d);
    }
  }
  __syncthreads();
  int M = total - chunk0; if (M > BINC) M = BINC;
  for (int j = t; j < M; j += 256) {
    int2 it = st[j];
    int b = it.y >> 9;
    binned[gbase[b] + (j - loff[b])] = it;
  }
}

__global__ __launch_bounds__(512) void bucket_finalize(const int2* __restrict__ binned,
                                                       const int* __restrict__ bkt_off,
                                                       int* __restrict__ row_ptr,
                                                       float* __restrict__ dis,
                                                       int* __restrict__ ev,
                                                       int n, int nbkt) {
  __shared__ int hist[BROW];
  __shared__ int sbuf[BROW];
  __shared__ int pre[BROW];
  __shared__ int front[BROW];
  const int b = blockIdx.x;
  const int t = threadIdx.x;
  const int row0 = b << 9;
  const int beg = bkt_off[b], end = bkt_off[b + 1];
  hist[t] = 0; front[t] = 0;
  __syncthreads();
  for (int j = beg + t; j < end; j += BROW)
    atomicAdd(&hist[binned[j].y - row0], 1);
  __syncthreads();
  const int x = hist[t];
  const int v = row0 + t;
  if (v < n) dis[v] = rsqrtf((float)x);
  sbuf[t] = x;
  __syncthreads();
  for (int off = 1; off < BROW; off <<= 1) {
    int val = (t >= off) ? sbuf[t - off] : 0;
    __syncthreads();
    sbuf[t] += val;
    __syncthreads();
  }
  pre[t] = sbuf[t] - x;
  if (v < n) row_ptr[v] = beg + pre[t];
  if (b == nbkt - 1 && t == 0) row_ptr[n] = end;
  __syncthreads();
  for (int j = beg + t; j < end; j += BROW) {
    int2 it = binned[j];
    int dl = it.y - row0;
    int slot = atomicAdd(&front[dl], 1);
    ev[beg + pre[dl] + slot] = it.x;
  }
}

// ---------------- weight prep ----------------

// Wft[c][r](bf16) = (W3@Wl)[r][c]; bf[c] = (b3@Wl + bl)[c]
__global__ __launch_bounds__(256) void fold_weights(const float* __restrict__ W3,
                                                    const float* __restrict__ Wl,
                                                    const float* __restrict__ b3,
                                                    const float* __restrict__ bl,
                                                    ushort* __restrict__ Wft,
                                                    float* __restrict__ bf) {
  int t = blockIdx.x * blockDim.x + threadIdx.x;
  if (t < NFEAT * NCP) {
    int r = t >> 4, c = t & 15;
    float s = 0.f;
    if (c < NCLS) {
      for (int k = 0; k < NFEAT; ++k) s += W3[r * NFEAT + k] * Wl[k * NCLS + c];
    }
    Wft[c * NFEAT + r] = f2bf(s);
  }
  if (t < NCP) {
    float s = 0.f;
    if (t < NCLS) {
      s = bl[t];
      for (int k = 0; k < NFEAT; ++k) s += b3[k] * Wl[k * NCLS + t];
    }
    bf[t] = s;
  }
}

// both weight transposes in one launch: Wt[n][k] (bf16) = W[k][n]
__global__ __launch_bounds__(256) void prep_w2(const float* __restrict__ W1,
                                               const float* __restrict__ W2,
                                               ushort* __restrict__ Wt1,
                                               ushort* __restrict__ Wt2) {
  int t = blockIdx.x * 256 + threadIdx.x;
  int u = t & 16383;
  int n = u >> 7, k = u & 127;
  if (t < 16384) Wt1[n * NFEAT + k] = f2bf(W1[k * NFEAT + n]);
  else           Wt2[n * NFEAT + k] = f2bf(W2[k * NFEAT + n]);
}

// ---- MFMA GEMM (layer 1): Cb[r](bf16 rows) = dis[r] * (A[r](fp32) @ W) ----

__global__ __launch_bounds__(256) void gemm_mfma(const float* __restrict__ A,
                                                 const ushort* __restrict__ Wt,
                                                 const float* __restrict__ dis,
                                                 ushort* __restrict__ Cb, int nrows) {
  __shared__ __align__(16) ushort Asm[64 * NFEAT];   // 16 KB
  const int tid = threadIdx.x;
  const int row0 = blockIdx.x * 64;
  {
    const int m = tid >> 2;
    const int kc = (tid & 3) * 32;
    const int gr = row0 + m;
    float4 f[8];
    if (gr < nrows) {
      #pragma unroll
      for (int q = 0; q < 8; ++q)
        f[q] = *(const float4*)&A[(size_t)gr * NFEAT + kc + q * 4];
    } else {
      #pragma unroll
      for (int q = 0; q < 8; ++q) f[q] = make_float4(0.f, 0.f, 0.f, 0.f);
    }
    #pragma unroll
    for (int q = 0; q < 4; ++q) {
      union { ushort us[8]; int4 v; } pk;
      const float* fp = (const float*)&f[q * 2];
      #pragma unroll
      for (int j = 0; j < 8; ++j) pk.us[j] = f2bf(fp[j]);
      int byte = (m * 256 + (kc + q * 8) * 2) ^ ((m & 7) << 4);
      *(int4*)((char*)Asm + byte) = pk.v;
    }
  }
  __syncthreads();
  const int wave = tid >> 6;
  const int lane = tid & 63;
  const int m0 = wave * 16;
  bf16x8 afr[4];
  #pragma unroll
  for (int ks = 0; ks < 4; ++ks) {
    int m = m0 + (lane & 15);
    int kk = ks * 32 + (lane >> 4) * 8;
    int byte = (m * 256 + kk * 2) ^ ((m & 7) << 4);
    afr[ks] = *(const bf16x8*)((const char*)Asm + byte);
  }
  f32x4 acc[8];
  #pragma unroll
  for (int c = 0; c < 8; ++c) acc[c] = (f32x4){0.f, 0.f, 0.f, 0.f};
  #pragma unroll
  for (int c = 0; c < 8; ++c) {
    #pragma unroll
    for (int ks = 0; ks < 4; ++ks) {
      int n = c * 16 + (lane & 15);
      int kk = ks * 32 + (lane >> 4) * 8;
      bf16x8 bfr = *(const bf16x8*)&Wt[n * NFEAT + kk];
      acc[c] = __builtin_amdgcn_mfma_f32_16x16x32_bf16(afr[ks], bfr, acc[c], 0, 0, 0);
    }
  }
  const int gr_base = row0 + m0 + (lane >> 4) * 4;
  float dr[4];
  #pragma unroll
  for (int r = 0; r < 4; ++r)
    dr[r] = (gr_base + r < nrows) ? dis[gr_base + r] : 0.f;
  #pragma unroll
  for (int c = 0; c < 8; ++c) {
    #pragma unroll
    for (int r = 0; r < 4; ++r) {
      int gr = gr_base + r;
      if (gr < nrows)
        Cb[(size_t)gr * NFEAT + c * 16 + (lane & 15)] = f2bf(acc[c][r] * dr[r]);
    }
  }
}

// ---- fused aggregate + GEMM ----
// Phase 1 (round-9 verified gather loop): per wave, 16 nodes; H[v] = relu(dis[v]*Σ hw[src] + bias)
// packed bf16 into swizzled LDS. Phase 2: MFMA tile, NCT col-tiles, epilogue ×dis[r] -> bf16 out.
// NCT=8: out rows 128 wide (next-layer h). NCT=1: out rows 16 wide (folded classifier G).

template<int NCT>
__global__ __launch_bounds__(256) void fused_agg_gemm(const ushort* __restrict__ hw,
                                                      const int* __restrict__ row_ptr,
                                                      const int* __restrict__ ev,
                                                      const float* __restrict__ dis,
                                                      const float* __restrict__ bias,
                                                      const ushort* __restrict__ Wt,
                                                      ushort* __restrict__ outB, int n) {
  __shared__ __align__(16) ushort Hs[64 * NFEAT];   // 16 KB
  const int tid = threadIdx.x;
  const int wave = tid >> 6;
  const int lane = tid & 63;
  const int half = lane >> 5;
  const int hl = lane & 31;
  const int row0 = blockIdx.x * 64;
  const float4 bs = *(const float4*)&bias[hl * 4];
  // ---- phase 1: aggregate 16 nodes per wave
  for (int q = 0; q < 16; ++q) {
    const int m = wave * 16 + q;
    const int v = row0 + m;
    float4 acc = make_float4(0.f, 0.f, 0.f, 0.f);
    if (v < n) {
      const int beg = row_ptr[v], end = row_ptr[v + 1];
      int e = beg + half;
      for (; e + 6 < end; e += 8) {    // 4 edges per half per iter -> 8 gathers in flight
        int s0 = ev[e];
        int s1 = ev[e + 2];
        int s2 = ev[e + 4];
        int s3 = ev[e + 6];
        ushort4 q0 = *(const ushort4*)&hw[(size_t)s0 * NFEAT + hl * 4];
        ushort4 q1 = *(const ushort4*)&hw[(size_t)s1 * NFEAT + hl * 4];
        ushort4 q2 = *(const ushort4*)&hw[(size_t)s2 * NFEAT + hl * 4];
        ushort4 q3 = *(const ushort4*)&hw[(size_t)s3 * NFEAT + hl * 4];
        acc.x += bf2f(q0.x) + bf2f(q1.x) + bf2f(q2.x) + bf2f(q3.x);
        acc.y += bf2f(q0.y) + bf2f(q1.y) + bf2f(q2.y) + bf2f(q3.y);
        acc.z += bf2f(q0.z) + bf2f(q1.z) + bf2f(q2.z) + bf2f(q3.z);
        acc.w += bf2f(q0.w) + bf2f(q1.w) + bf2f(q2.w) + bf2f(q3.w);
      }
      for (; e < end; e += 2) {
        int s = ev[e];
        ushort4 q4 = *(const ushort4*)&hw[(size_t)s * NFEAT + hl * 4];
        acc.x += bf2f(q4.x); acc.y += bf2f(q4.y);
        acc.z += bf2f(q4.z); acc.w += bf2f(q4.w);
      }
      acc.x += __shfl_xor(acc.x, 32);
      acc.y += __shfl_xor(acc.y, 32);
      acc.z += __shfl_xor(acc.z, 32);
      acc.w += __shfl_xor(acc.w, 32);
    }
    if (half == 0) {
      float r0 = 0.f, r1 = 0.f, r2 = 0.f, r3 = 0.f;
      if (v < n) {
        const float dv = dis[v];
        r0 = fmaxf(fmaf(acc.x, dv, bs.x), 0.f);
        r1 = fmaxf(fmaf(acc.y, dv, bs.y), 0.f);
        r2 = fmaxf(fmaf(acc.z, dv, bs.z), 0.f);
        r3 = fmaxf(fmaf(acc.w, dv, bs.w), 0.f);
      }
      union { ushort us[4]; uint2 q2; } pk;
      pk.us[0] = f2bf(r0); pk.us[1] = f2bf(r1);
      pk.us[2] = f2bf(r2); pk.us[3] = f2bf(r3);
      int byte = (m * 256 + hl * 8) ^ ((m & 7) << 4);
      *(uint2*)((char*)Hs + byte) = pk.q2;
    }
  }
  __syncthreads();
  // ---- phase 2: MFMA
  const int m0 = wave * 16;
  bf16x8 afr[4];
  #pragma unroll
  for (int ks = 0; ks < 4; ++ks) {
    int m = m0 + (lane & 15);
    int kk = ks * 32 + (lane >> 4) * 8;
    int byte = (m * 256 + kk * 2) ^ ((m & 7) << 4);
    afr[ks] = *(const bf16x8*)((const char*)Hs + byte);
  }
  f32x4 acc[NCT];
  #pragma unroll
  for (int c = 0; c < NCT; ++c) acc[c] = (f32x4){0.f, 0.f, 0.f, 0.f};
  #pragma unroll
  for (int c = 0; c < NCT; ++c) {
    #pragma unroll
    for (int ks = 0; ks < 4; ++ks) {
      int nn = c * 16 + (lane & 15);
      int kk = ks * 32 + (lane >> 4) * 8;
      bf16x8 bfr = *(const bf16x8*)&Wt[nn * NFEAT + kk];
      acc[c] = __builtin_amdgcn_mfma_f32_16x16x32_bf16(afr[ks], bfr, acc[c], 0, 0, 0);
    }
  }
  const int gr_base = row0 + m0 + (lane >> 4) * 4;
  float dr[4];
  #pragma unroll
  for (int r = 0; r < 4; ++r)
    dr[r] = (gr_base + r < n) ? dis[gr_base + r] : 0.f;
  #pragma unroll
  for (int c = 0; c < NCT; ++c) {
    #pragma unroll
    for (int r = 0; r < 4; ++r) {
      int gr = gr_base + r;
      if (gr < n)
        outB[(size_t)gr * (NCT * 16) + c * 16 + (lane & 15)] = f2bf(acc[c][r] * dr[r]);
    }
  }
}

// ---------------- fused aggregation over bf16 G (16 feats) + bias + log_softmax --------

__global__ __launch_bounds__(256) void agg_logits(const ushort* __restrict__ Gb,
                                                  const int* __restrict__ row_ptr,
                                                  const int* __restrict__ ev,
                                                  const float* __restrict__ dis,
                                                  const float* __restrict__ bf,
                                                  float* __restrict__ out, int n) {
  const int wave = threadIdx.x >> 6;
  const int lane = threadIdx.x & 63;
  const int v = blockIdx.x * 4 + wave;
  if (v >= n) return;
  const int beg = row_ptr[v], end = row_ptr[v + 1];
  const int g = lane >> 4;           // 4 edge groups
  const int f = lane & 15;           // feature (class) index
  float acc = 0.f;
  int e = beg + g;
  for (; e + 4 < end; e += 8) {
    int s0 = ev[e];
    int s1 = ev[e + 4];
    acc += bf2f(Gb[(size_t)s0 * NCP + f]) + bf2f(Gb[(size_t)s1 * NCP + f]);
  }
  for (; e < end; e += 4) {
    acc += bf2f(Gb[(size_t)ev[e] * NCP + f]);
  }
  acc += __shfl_xor(acc, 16);
  acc += __shfl_xor(acc, 32);
  float logit = dis[v] * acc + bf[f];
  float pv = (f < NCLS) ? logit : -INFINITY;
  float m = pv;
  #pragma unroll
  for (int s = 8; s >= 1; s >>= 1) m = fmaxf(m, __shfl_xor(m, s));
  float ex = (f < NCLS) ? expf(logit - m) : 0.f;
  float ssum = ex;
  #pragma unroll
  for (int s = 8; s >= 1; s >>= 1) ssum += __shfl_xor(ssum, s);
  float lse = m + logf(ssum);
  if (g == 0 && f < NCLS) out[(size_t)v * NCLS + f] = logit - lse;
}

// ---------------- launcher ----------------

extern "C" void kernel_launch(void* const* d_in, const int* in_sizes, int n_in,
                              void* d_out, int out_size, void* d_ws, size_t ws_size,
                              hipStream_t stream) {
  const float* x  = (const float*)d_in[0];
  const int*   ei = (const int*)d_in[1];
  const float* W1 = (const float*)d_in[2];
  const float* b1 = (const float*)d_in[3];
  const float* W2 = (const float*)d_in[4];
  const float* b2 = (const float*)d_in[5];
  const float* W3 = (const float*)d_in[6];
  const float* b3 = (const float*)d_in[7];
  const float* Wl = (const float*)d_in[8];
  const float* bl = (const float*)d_in[9];
  float* out = (float*)d_out;

  const int nN = in_sizes[0] / NFEAT;   // 100000
  const int nE = in_sizes[1] / 2;       // 1600000
  const int total = nN + nE;
  const int nbkt = (nN + BROW - 1) >> 9;          // 196
  const int nbBin = (total + BINC - 1) / BINC;

  char* ws = (char*)d_ws;
  int*    bkt_cnt = (int*)ws;     ws += alignup(256 * 4);
  int*    bkt_off = (int*)ws;     ws += alignup(257 * 4);
  int*    gfront  = (int*)ws;     ws += alignup(256 * 4);
  int*    row_ptr = (int*)ws;     ws += alignup((size_t)(nN + 1) * 4);
  float*  dis     = (float*)ws;   ws += alignup((size_t)nN * 4);
  float*  bfv     = (float*)ws;   ws += alignup((size_t)NCP * 4);
  ushort* Wft     = (ushort*)ws;  ws += alignup((size_t)NCP * NFEAT * 2);
  ushort* Wt1     = (ushort*)ws;  ws += alignup((size_t)NFEAT * NFEAT * 2);
  ushort* Wt2     = (ushort*)ws;  ws += alignup((size_t)NFEAT * NFEAT * 2);
  int2*   binned  = (int2*)ws;    ws += alignup((size_t)total * 8);
  int*    ev      = (int*)ws;     ws += alignup((size_t)total * 4);
  ushort* hb      = (ushort*)ws;  ws += alignup((size_t)nN * NFEAT * 2);  // layer-1 gemm out
  ushort* hb2     = (ushort*)ws;  ws += alignup((size_t)nN * NFEAT * 2);  // layer-2 fused out
  ushort* Gb      = (ushort*)ws;  ws += alignup((size_t)nN * NCP * 2);    // folded logits (bf16)

  // ---- CSR build
  hipMemsetAsync(bkt_cnt, 0, 256 * sizeof(int), stream);
  bucket_hist<<<512, 256, 0, stream>>>(ei + nE, bkt_cnt, nE, nbkt);
  bkt_scan<<<1, 256, 0, stream>>>(bkt_cnt, bkt_off, gfront, nN, nbkt);
  bin_items<<<nbBin, 256, 0, stream>>>(ei, nE, total, nbkt, gfront, binned);
  bucket_finalize<<<nbkt, BROW, 0, stream>>>(binned, bkt_off, row_ptr, dis, ev, nN, nbkt);

  // ---- weight prep
  fold_weights<<<8, 256, 0, stream>>>(W3, Wl, b3, bl, Wft, bfv);
  prep_w2<<<128, 256, 0, stream>>>(W1, W2, Wt1, Wt2);

  const int gemm_grid = (nN + 63) / 64;
  const int node_grid = (nN + 3) / 4;

  // layer 1 GEMM: hb = dis * (x @ W1)
  gemm_mfma<<<gemm_grid, 256, 0, stream>>>(x, Wt1, dis, hb, nN);
  // fused: H1 = relu(dis*Agg(hb)+b1); hb2 = dis * (H1 @ W2)
  fused_agg_gemm<8><<<gemm_grid, 256, 0, stream>>>(hb, row_ptr, ev, dis, b1, Wt2, hb2, nN);
  // fused: H2 = relu(dis*Agg(hb2)+b2); Gb = dis * (H2 @ (W3@Wl))
  fused_agg_gemm<1><<<gemm_grid, 256, 0, stream>>>(hb2, row_ptr, ev, dis, b2, Wft, Gb, nN);
  // logits = dis*Agg(Gb) + bf; log_softmax
  agg_logits<<<node_grid, 256, 0, stream>>>(Gb, row_ptr, ev, dis, bfv, out, nN);
}